// Round 4
// baseline (127.715 us; speedup 1.0000x reference)
//
#include <hip/hip_runtime.h>

#define DIM     1024
#define BATCH   512
#define OUTD    5377
#define NHEADS  10
#define NLAYERS 5
#define LDK     72   // padded bf16 leading dim (144 B -> benign bank aliasing)

typedef __attribute__((ext_vector_type(4))) float f32x4;
typedef __attribute__((ext_vector_type(8))) short bf16x8;

__device__ __forceinline__ unsigned short f2bf(float f) {
    unsigned u = __builtin_bit_cast(unsigned, f);
    u = (u + 0x7FFFu + ((u >> 16) & 1u)) >> 16;
    return (unsigned short)u;
}
__device__ __forceinline__ float bf2f(unsigned short h) {
    unsigned u = ((unsigned)h) << 16;
    return __builtin_bit_cast(float, u);
}
__device__ __forceinline__ unsigned pk2(float a, float b) {
    return (unsigned)f2bf(a) | ((unsigned)f2bf(b) << 16);
}

// ---------------- grouping: bucket batches by rule_len ----------------
__global__ void group_kernel(const int* __restrict__ rule_len,
                             int* __restrict__ bidx,
                             int* __restrict__ gstart,
                             int* __restrict__ gcount) {
    __shared__ int s_count[NHEADS];
    __shared__ int s_fill[NHEADS];
    int t = threadIdx.x;
    if (t < NHEADS) s_count[t] = 0;
    __syncthreads();
    int h = rule_len[t];
    atomicAdd(&s_count[h], 1);
    __syncthreads();
    if (t == 0) {
        int acc = 0;
        for (int i = 0; i < NHEADS; ++i) {
            gstart[i] = acc;
            gcount[i] = s_count[i];
            s_fill[i] = acc;
            acc += s_count[i];
        }
    }
    __syncthreads();
    int pos = atomicAdd(&s_fill[h], 1);
    bidx[pos] = t;
}

// ---------------- latent f32 -> bf16 ----------------
__global__ void convert_latent(const float* __restrict__ in,
                               unsigned short* __restrict__ out) {
    int i = blockIdx.x * blockDim.x + threadIdx.x;   // one float4 per thread
    float4 v = ((const float4*)in)[i];
    ushort4 o;
    o.x = f2bf(v.x); o.y = f2bf(v.y); o.z = f2bf(v.z); o.w = f2bf(v.w);
    ((ushort4*)out)[i] = o;
}

// ---------------- MLP layer: C = A @ W^T + bias  (MFMA, W hi/lo, pipelined) --
__global__ __launch_bounds__(256) void mlp_mfma(
    const unsigned short* __restrict__ A,
    const float* __restrict__ W,
    const float* __restrict__ bias,
    unsigned short* __restrict__ C)
{
    __shared__ __align__(16) unsigned short As[2][32][LDK];
    __shared__ __align__(16) unsigned short Whi[2][32][LDK];
    __shared__ __align__(16) unsigned short Wlo[2][32][LDK];

    const int tid = threadIdx.x;
    const int n0 = blockIdx.x * 32;
    const int m0 = blockIdx.y * 32;
    const int lane = tid & 63;
    const int wid = tid >> 6;
    const int wm = (wid >> 1) * 16;
    const int wn = (wid & 1) * 16;

    f32x4 acc = {0.f, 0.f, 0.f, 0.f};

    const int ar = tid >> 3;          // 0..31
    const int ac = (tid & 7) * 8;     // 0..56 bf16 units
    const int wr = tid >> 4;          // 0..15
    const int wc = (tid & 15) * 4;    // 0..60 f32 units

    const unsigned short* Ap = A + (size_t)(m0 + ar) * DIM + ac;
    const float* Wp0 = W + (size_t)(n0 + wr) * DIM + wc;
    const float* Wp1 = W + (size_t)(n0 + wr + 16) * DIM + wc;

    uint4  ra  = *(const uint4*)(Ap);
    float4 rw0 = *(const float4*)(Wp0);
    float4 rw1 = *(const float4*)(Wp1);

    for (int t = 0; t < DIM / 64; ++t) {
        const int cur = t & 1;
        *(uint4*)&As[cur][ar][ac] = ra;
        {
            ushort4 hi, lo;
            hi.x = f2bf(rw0.x); lo.x = f2bf(rw0.x - bf2f(hi.x));
            hi.y = f2bf(rw0.y); lo.y = f2bf(rw0.y - bf2f(hi.y));
            hi.z = f2bf(rw0.z); lo.z = f2bf(rw0.z - bf2f(hi.z));
            hi.w = f2bf(rw0.w); lo.w = f2bf(rw0.w - bf2f(hi.w));
            *(ushort4*)&Whi[cur][wr][wc] = hi;
            *(ushort4*)&Wlo[cur][wr][wc] = lo;
            hi.x = f2bf(rw1.x); lo.x = f2bf(rw1.x - bf2f(hi.x));
            hi.y = f2bf(rw1.y); lo.y = f2bf(rw1.y - bf2f(hi.y));
            hi.z = f2bf(rw1.z); lo.z = f2bf(rw1.z - bf2f(hi.z));
            hi.w = f2bf(rw1.w); lo.w = f2bf(rw1.w - bf2f(hi.w));
            *(ushort4*)&Whi[cur][wr + 16][wc] = hi;
            *(ushort4*)&Wlo[cur][wr + 16][wc] = lo;
        }
        __syncthreads();
        if (t < DIM / 64 - 1) {
            const int k0 = (t + 1) * 64;
            ra  = *(const uint4*)(Ap + k0);
            rw0 = *(const float4*)(Wp0 + k0);
            rw1 = *(const float4*)(Wp1 + k0);
        }
        #pragma unroll
        for (int kk = 0; kk < 2; ++kk) {
            const int ko = kk * 32 + (lane >> 4) * 8;
            bf16x8 a  = *(const bf16x8*)&As[cur][wm + (lane & 15)][ko];
            bf16x8 bh = *(const bf16x8*)&Whi[cur][wn + (lane & 15)][ko];
            bf16x8 bl = *(const bf16x8*)&Wlo[cur][wn + (lane & 15)][ko];
            acc = __builtin_amdgcn_mfma_f32_16x16x32_bf16(a, bh, acc, 0, 0, 0);
            acc = __builtin_amdgcn_mfma_f32_16x16x32_bf16(a, bl, acc, 0, 0, 0);
        }
    }

    const int cn = n0 + wn + (lane & 15);
    const float bn = bias[cn];
    const int rbase = m0 + wm + (lane >> 4) * 4;
    #pragma unroll
    for (int j = 0; j < 4; ++j) {
        C[(size_t)(rbase + j) * DIM + cn] = f2bf(acc[j] + bn);
    }
}

// ------- grouped head GEMM: 64x32 tile, raw-barrier pipeline, 2-deep --------
__global__ __launch_bounds__(256, 5) void head_mfma(
    const unsigned short* __restrict__ H,   // BATCH x DIM bf16
    const float* __restrict__ Wh,           // NHEADS x OUTD x DIM f32
    const float* __restrict__ bh,           // NHEADS x OUTD f32
    const int* __restrict__ bidx,
    const int* __restrict__ gstart,
    const int* __restrict__ gcount,
    float* __restrict__ out)                // BATCH x OUTD f32
{
    const int head = blockIdx.z;
    const int cnt = gcount[head];
    const int m0 = blockIdx.y * 64;
    if (m0 >= cnt) return;
    const int n0 = blockIdx.x * 32;

    __shared__ __align__(16) unsigned short As[2][64][LDK];
    __shared__ __align__(16) unsigned short Ws[2][32][LDK];
    __shared__ int s_b[64];

    const int tid = threadIdx.x;
    if (tid < 64) {
        int mi = m0 + tid;
        s_b[tid] = (mi < cnt) ? bidx[gstart[head] + mi] : -1;
    }
    __syncthreads();

    const int lane = tid & 63;
    const int wid = tid >> 6;
    const int wm = (wid >> 1) * 32;   // 0 or 32
    const int wn = (wid & 1) * 16;    // 0 or 16

    f32x4 acc[2] = {};

    // A staging: rows ar and ar+32, 16 B each
    const int ar = tid >> 3;          // 0..31
    const int ac = (tid & 7) * 8;     // bf16 units
    int b0 = s_b[ar];       if (b0 < 0) b0 = 0;
    int b1 = s_b[ar + 32];  if (b1 < 0) b1 = 0;
    const unsigned short* Ap0 = H + (size_t)b0 * DIM + ac;
    const unsigned short* Ap1 = H + (size_t)b1 * DIM + ac;

    // W staging: one row per thread (32 rows), 8 consecutive f32
    const int wr = tid >> 3;          // 0..31
    const int wc = (tid & 7) * 8;     // f32 units == bf16 dest index
    int wrow = n0 + wr; if (wrow > OUTD - 1) wrow = OUTD - 1;
    const float* Wp = Wh + (size_t)head * OUTD * DIM + (size_t)wrow * DIM + wc;

    uint4  pa0[2], pa1[2];
    float4 pw0[2], pw1[2];

    pa0[0] = *(const uint4*)(Ap0);
    pa1[0] = *(const uint4*)(Ap1);
    pw0[0] = *(const float4*)(Wp);
    pw1[0] = *(const float4*)(Wp + 4);
    pa0[1] = *(const uint4*)(Ap0 + 64);
    pa1[1] = *(const uint4*)(Ap1 + 64);
    pw0[1] = *(const float4*)(Wp + 64);
    pw1[1] = *(const float4*)(Wp + 68);

    #pragma unroll
    for (int t = 0; t < DIM / 64; ++t) {
        const int cur = t & 1;
        *(uint4*)&As[cur][ar][ac]      = pa0[cur];
        *(uint4*)&As[cur][ar + 32][ac] = pa1[cur];
        uint4 wp;
        wp.x = pk2(pw0[cur].x, pw0[cur].y);
        wp.y = pk2(pw0[cur].z, pw0[cur].w);
        wp.z = pk2(pw1[cur].x, pw1[cur].y);
        wp.w = pk2(pw1[cur].z, pw1[cur].w);
        *(uint4*)&Ws[cur][wr][wc] = wp;
        // LDS-only drain + raw barrier: global prefetch stays in flight.
        asm volatile("s_waitcnt lgkmcnt(0)" ::: "memory");
        __builtin_amdgcn_s_barrier();
        __builtin_amdgcn_sched_barrier(0);
        if (t + 2 < DIM / 64) {
            const int k0 = (t + 2) * 64;
            pa0[cur] = *(const uint4*)(Ap0 + k0);
            pa1[cur] = *(const uint4*)(Ap1 + k0);
            pw0[cur] = *(const float4*)(Wp + k0);
            pw1[cur] = *(const float4*)(Wp + k0 + 4);
        }
        #pragma unroll
        for (int kk = 0; kk < 2; ++kk) {
            const int ko = kk * 32 + (lane >> 4) * 8;
            bf16x8 a0 = *(const bf16x8*)&As[cur][wm + (lane & 15)][ko];
            bf16x8 a1 = *(const bf16x8*)&As[cur][wm + 16 + (lane & 15)][ko];
            bf16x8 w0 = *(const bf16x8*)&Ws[cur][wn + (lane & 15)][ko];
            acc[0] = __builtin_amdgcn_mfma_f32_16x16x32_bf16(a0, w0, acc[0], 0, 0, 0);
            acc[1] = __builtin_amdgcn_mfma_f32_16x16x32_bf16(a1, w0, acc[1], 0, 0, 0);
        }
    }

    const float* bhL = bh + (size_t)head * OUTD;
    const int n = n0 + wn + (lane & 15);
    if (n < OUTD) {
        const float bn = bhL[n];
        #pragma unroll
        for (int fm = 0; fm < 2; ++fm) {
            #pragma unroll
            for (int j = 0; j < 4; ++j) {
                int mi = wm + fm * 16 + (lane >> 4) * 4 + j;
                int b = s_b[mi];
                if (b >= 0) out[(size_t)b * OUTD + n] = acc[fm][j] + bn;
            }
        }
    }
}

extern "C" void kernel_launch(void* const* d_in, const int* in_sizes, int n_in,
                              void* d_out, int out_size, void* d_ws, size_t ws_size,
                              hipStream_t stream) {
    const float* latent   = (const float*)d_in[0];
    const float* W_mlp    = (const float*)d_in[1];
    const float* b_mlp    = (const float*)d_in[2];
    const float* W_heads  = (const float*)d_in[3];
    const float* b_heads  = (const float*)d_in[4];
    const int*   rule_len = (const int*)d_in[5];
    float* out = (float*)d_out;

    unsigned short* h0 = (unsigned short*)d_ws;
    unsigned short* h1 = h0 + (size_t)BATCH * DIM;
    int* bidx   = (int*)(h1 + (size_t)BATCH * DIM);
    int* gstart = bidx + BATCH;
    int* gcount = gstart + 16;

    group_kernel<<<1, BATCH, 0, stream>>>(rule_len, bidx, gstart, gcount);
    convert_latent<<<(BATCH * DIM / 4) / 256, 256, 0, stream>>>(latent, h0);

    dim3 mgrid(DIM / 32, BATCH / 32);
    const unsigned short* src = h0;
    unsigned short* dst = h1;
    for (int l = 0; l < NLAYERS; ++l) {
        mlp_mfma<<<mgrid, 256, 0, stream>>>(src,
                                            W_mlp + (size_t)l * DIM * DIM,
                                            b_mlp + (size_t)l * DIM,
                                            dst);
        unsigned short* t = (unsigned short*)src;
        src = dst;
        dst = t;
    }

    dim3 hgrid((OUTD + 31) / 32, BATCH / 64, NHEADS);
    head_mfma<<<hgrid, 256, 0, stream>>>(src, W_heads, b_heads,
                                         bidx, gstart, gcount, out);
}